// Round 1
// baseline (1208.127 us; speedup 1.0000x reference)
//
#include <hip/hip_runtime.h>
#include <hip/hip_bf16.h>
#include <math.h>

#define N_NODES 50000
#define N_EDGES 640000
#define DIM 128
#define LDP 136   // padded LDS row length in bf16 elems (row stride 272B -> 2-way bank alias, free)

typedef __attribute__((ext_vector_type(8))) short short8;
typedef __attribute__((ext_vector_type(4))) float floatx4;

__device__ __forceinline__ unsigned short f2bf(float f) {
    unsigned int u = __float_as_uint(f);
    u += 0x7FFFu + ((u >> 16) & 1u);       // round-to-nearest-even
    return (unsigned short)(u >> 16);
}
__device__ __forceinline__ float bf2f(unsigned short h) {
    return __uint_as_float(((unsigned int)h) << 16);
}

// ---------------------------------------------------------------------------
// Kernel 1: Y = X @ W^T + b for W in {Aw,Bw,Dw,Ew}, via bf16 MFMA 16x16x32.
// Block: 256 thr (4 waves), tile = 64 rows x 128 cols. blockIdx.y picks matrix.
// ---------------------------------------------------------------------------
__global__ __launch_bounds__(256) void node_gemm(
    const float* __restrict__ x,
    const float* __restrict__ w0, const float* __restrict__ b0,
    const float* __restrict__ w1, const float* __restrict__ b1,
    const float* __restrict__ w2, const float* __restrict__ b2,
    const float* __restrict__ w3, const float* __restrict__ b3,
    float* __restrict__ o0, float* __restrict__ o1,
    float* __restrict__ o2, float* __restrict__ o3)
{
    __shared__ unsigned short Xs[64 * LDP];
    __shared__ unsigned short Ws[128 * LDP];
    const int tid  = threadIdx.x;
    const int mblk = blockIdx.x * 64;
    const int mid  = blockIdx.y;
    const float* W = mid == 0 ? w0 : mid == 1 ? w1 : mid == 2 ? w2 : w3;
    const float* B = mid == 0 ? b0 : mid == 1 ? b1 : mid == 2 ? b2 : b3;
    float*       O = mid == 0 ? o0 : mid == 1 ? o1 : mid == 2 ? o2 : o3;

    // stage X tile (64x128 f32 -> bf16 LDS)
#pragma unroll
    for (int i = 0; i < 8; ++i) {
        int slot = tid + i * 256;
        int row = slot >> 5, c4 = (slot & 31) << 2;
        int rg = mblk + row;
        float4 v = make_float4(0.f, 0.f, 0.f, 0.f);
        if (rg < N_NODES) v = *(const float4*)(x + (size_t)rg * DIM + c4);
        unsigned short* p = &Xs[row * LDP + c4];
        p[0] = f2bf(v.x); p[1] = f2bf(v.y); p[2] = f2bf(v.z); p[3] = f2bf(v.w);
    }
    // stage W (128x128 f32 -> bf16 LDS), row-major W[n][k]
#pragma unroll
    for (int i = 0; i < 16; ++i) {
        int slot = tid + i * 256;
        int row = slot >> 5, c4 = (slot & 31) << 2;
        float4 v = *(const float4*)(W + row * DIM + c4);
        unsigned short* p = &Ws[row * LDP + c4];
        p[0] = f2bf(v.x); p[1] = f2bf(v.y); p[2] = f2bf(v.z); p[3] = f2bf(v.w);
    }
    __syncthreads();

    const int wave = tid >> 6, lane = tid & 63;
    const int q = lane >> 4, r = lane & 15;
    floatx4 acc[8];
#pragma unroll
    for (int i = 0; i < 8; ++i) acc[i] = (floatx4)(0.f);
    const int arow = wave * 16 + r;
#pragma unroll
    for (int kk = 0; kk < 4; ++kk) {
        short8 a = *(const short8*)&Xs[arow * LDP + kk * 32 + q * 8];
#pragma unroll
        for (int nt = 0; nt < 8; ++nt) {
            short8 b = *(const short8*)&Ws[(nt * 16 + r) * LDP + kk * 32 + q * 8];
            acc[nt] = __builtin_amdgcn_mfma_f32_16x16x32_bf16(a, b, acc[nt], 0, 0, 0);
        }
    }
    // epilogue: D[row=q*4+reg][col=r] per (mt=wave tile, nt)
#pragma unroll
    for (int nt = 0; nt < 8; ++nt) {
        int col = nt * 16 + r;
        float bv = B[col];
#pragma unroll
        for (int reg = 0; reg < 4; ++reg) {
            int rg = mblk + wave * 16 + q * 4 + reg;
            if (rg < N_NODES) O[(size_t)rg * DIM + col] = acc[nt][reg] + bv;
        }
    }
}

// ---------------------------------------------------------------------------
// Kernel 2: fused edge pipeline. Ce = e@Cw^T (MFMA), e_ij = Ce+Cb+Dx[dst]+Ex[src],
// e_out = e + relu(BN_e(e_ij)), atomics: num[dst]+=sig*Bx[src], den[dst]+=sig.
// Tile = 64 edges x 128 cols; 640000/64 = 10000 blocks exactly.
// ---------------------------------------------------------------------------
__global__ __launch_bounds__(256) void edge_kernel(
    const float* __restrict__ e,
    const float* __restrict__ Cw, const float* __restrict__ Cb,
    const int* __restrict__ ei,
    const float* __restrict__ Dx, const float* __restrict__ Ex,
    const float* __restrict__ Bx,
    const float* __restrict__ g,  const float* __restrict__ bt,
    const float* __restrict__ mn, const float* __restrict__ vr,
    float* __restrict__ num, float* __restrict__ den,
    float* __restrict__ e_out)
{
    __shared__ unsigned short Es[64 * LDP];
    __shared__ unsigned short Ws[128 * LDP];
    __shared__ int srcS[64], dstS[64];
    const int tid  = threadIdx.x;
    const int mblk = blockIdx.x * 64;

    if (tid < 64) {
        srcS[tid] = ei[mblk + tid];            // edge_index[0] = source
        dstS[tid] = ei[N_EDGES + mblk + tid];  // edge_index[1] = target
    }
#pragma unroll
    for (int i = 0; i < 8; ++i) {
        int slot = tid + i * 256;
        int row = slot >> 5, c4 = (slot & 31) << 2;
        float4 v = *(const float4*)(e + (size_t)(mblk + row) * DIM + c4);
        unsigned short* p = &Es[row * LDP + c4];
        p[0] = f2bf(v.x); p[1] = f2bf(v.y); p[2] = f2bf(v.z); p[3] = f2bf(v.w);
    }
#pragma unroll
    for (int i = 0; i < 16; ++i) {
        int slot = tid + i * 256;
        int row = slot >> 5, c4 = (slot & 31) << 2;
        float4 v = *(const float4*)(Cw + row * DIM + c4);
        unsigned short* p = &Ws[row * LDP + c4];
        p[0] = f2bf(v.x); p[1] = f2bf(v.y); p[2] = f2bf(v.z); p[3] = f2bf(v.w);
    }
    __syncthreads();

    const int wave = tid >> 6, lane = tid & 63;
    const int q = lane >> 4, r = lane & 15;
    floatx4 acc[8];
#pragma unroll
    for (int i = 0; i < 8; ++i) acc[i] = (floatx4)(0.f);
    const int arow = wave * 16 + r;
#pragma unroll
    for (int kk = 0; kk < 4; ++kk) {
        short8 a = *(const short8*)&Es[arow * LDP + kk * 32 + q * 8];
#pragma unroll
        for (int nt = 0; nt < 8; ++nt) {
            short8 b = *(const short8*)&Ws[(nt * 16 + r) * LDP + kk * 32 + q * 8];
            acc[nt] = __builtin_amdgcn_mfma_f32_16x16x32_bf16(a, b, acc[nt], 0, 0, 0);
        }
    }

#pragma unroll
    for (int nt = 0; nt < 8; ++nt) {
        int col = nt * 16 + r;
        float cb = Cb[col];
        float sc = g[col] * rsqrtf(vr[col] + 1e-5f);
        float sh = bt[col] - mn[col] * sc;
#pragma unroll
        for (int reg = 0; reg < 4; ++reg) {
            int rl = wave * 16 + q * 4 + reg;
            int rg = mblk + rl;
            int dd = dstS[rl], ss = srcS[rl];
            float eij = acc[nt][reg] + cb
                      + Dx[(size_t)dd * DIM + col] + Ex[(size_t)ss * DIM + col];
            float sg = 1.f / (1.f + __expf(-eij));
            atomicAdd(&num[(size_t)dd * DIM + col], sg * Bx[(size_t)ss * DIM + col]);
            atomicAdd(&den[(size_t)dd * DIM + col], sg);
            float bn = eij * sc + sh;
            e_out[(size_t)rg * DIM + col] = bf2f(Es[rl * LDP + col]) + (bn > 0.f ? bn : 0.f);
        }
    }
}

// ---------------------------------------------------------------------------
// Kernel 3: x_out = x + relu(BN_x(Ax + num/(den+eps)))
// ---------------------------------------------------------------------------
__global__ __launch_bounds__(256) void node_final(
    const float* __restrict__ x,  const float* __restrict__ Ax,
    const float* __restrict__ num, const float* __restrict__ den,
    const float* __restrict__ g,  const float* __restrict__ bt,
    const float* __restrict__ mn, const float* __restrict__ vr,
    float* __restrict__ x_out)
{
    int idx = (blockIdx.x * 256 + threadIdx.x) * 4;
    float4 a  = *(const float4*)(Ax + idx);
    float4 nm = *(const float4*)(num + idx);
    float4 dn = *(const float4*)(den + idx);
    float4 xv = *(const float4*)(x + idx);
    int col = idx & (DIM - 1);
    float av[4] = {a.x, a.y, a.z, a.w};
    float nv[4] = {nm.x, nm.y, nm.z, nm.w};
    float dv[4] = {dn.x, dn.y, dn.z, dn.w};
    float xs[4] = {xv.x, xv.y, xv.z, xv.w};
    float ov[4];
#pragma unroll
    for (int j = 0; j < 4; ++j) {
        float sc = g[col + j] * rsqrtf(vr[col + j] + 1e-5f);
        float sh = bt[col + j] - mn[col + j] * sc;
        float v = av[j] + nv[j] / (dv[j] + 1e-6f);
        float bn = v * sc + sh;
        ov[j] = xs[j] + (bn > 0.f ? bn : 0.f);
    }
    *(float4*)(x_out + idx) = make_float4(ov[0], ov[1], ov[2], ov[3]);
}

extern "C" void kernel_launch(void* const* d_in, const int* in_sizes, int n_in,
                              void* d_out, int out_size, void* d_ws, size_t ws_size,
                              hipStream_t stream) {
    const float* x  = (const float*)d_in[0];
    const float* e  = (const float*)d_in[1];
    const float* Aw = (const float*)d_in[2];  const float* Ab = (const float*)d_in[3];
    const float* Bw = (const float*)d_in[4];  const float* Bb = (const float*)d_in[5];
    const float* Cw = (const float*)d_in[6];  const float* Cb = (const float*)d_in[7];
    const float* Dw = (const float*)d_in[8];  const float* Db = (const float*)d_in[9];
    const float* Ew = (const float*)d_in[10]; const float* Eb = (const float*)d_in[11];
    const float* gx = (const float*)d_in[12]; const float* btx = (const float*)d_in[13];
    const float* mnx = (const float*)d_in[14]; const float* vrx = (const float*)d_in[15];
    const float* ge = (const float*)d_in[16]; const float* bte = (const float*)d_in[17];
    const float* mne = (const float*)d_in[18]; const float* vre = (const float*)d_in[19];
    const int*   ei = (const int*)d_in[20];

    const size_t NF = (size_t)N_NODES * DIM;   // 6.4M floats
    float* ws  = (float*)d_ws;
    float* Ax  = ws;
    float* Bx  = ws + NF;
    float* Dx  = ws + 2 * NF;
    float* Ex  = ws + 3 * NF;
    float* num = ws + 4 * NF;
    float* den = ws + 5 * NF;

    float* x_out = (float*)d_out;
    float* e_out = x_out + NF;

    // zero num+den (contiguous)
    hipMemsetAsync(num, 0, 2 * NF * sizeof(float), stream);

    dim3 g1((N_NODES + 63) / 64, 4);
    node_gemm<<<g1, 256, 0, stream>>>(x, Aw, Ab, Bw, Bb, Dw, Db, Ew, Eb, Ax, Bx, Dx, Ex);

    edge_kernel<<<N_EDGES / 64, 256, 0, stream>>>(e, Cw, Cb, ei, Dx, Ex, Bx,
                                                  ge, bte, mne, vre, num, den, e_out);

    node_final<<<(int)(NF / 4 / 256), 256, 0, stream>>>(x, Ax, num, den,
                                                        gx, btx, mnx, vrx, x_out);
}